// Round 19
// baseline (266.806 us; speedup 1.0000x reference)
//
#include <hip/hip_runtime.h>

#define GH 135
#define GW 240
#define HH 1080
#define WW 1920
#define HWPX (HH*WW)
#define NP 12
#define IT 2               // anchor block-rows per WG (i-strip)
#define JT 12              // anchor blocks (j) per WG
#define NBG 6              // anchor pairs per it-row
#define NIG 68             // ceil(GH/IT)
#define NJG 20             // GW/JT
#define TROWS (IT+8)       // 10 staged target block-rows
#define TBLK (JT+8)        // 20 staged target blocks per dy-row
#define DSTR (TBLK*64+8)   // 1288 dw: 2-quad row rotation (r12 conflict fix)
#define UNITS_ROW (TBLK*16)// 320 16B-units per dy-row (= exactly 5 waves)
#define UNITS_TOT (TROWS*UNITS_ROW) // 3200
#define NTHR 256
#define NACT 216           // 9 dy * (2 it * 6 bg * 2 yh)
#define TT_DW (TROWS*DSTR) // 12880 dw = 51520 B -> 3 WG/CU
#define NWG (NIG*NJG)      // 1360 = 8*170 (XCD-exact)
#define NBLK (GH*GW)       // 32400 target blocks
#define ST2_FINAL_OFF 262144   // double-index into d_out for final stsum

// Round-19: HALVE the hot-loop VALU. Diagnosis: all 8 prior results fit
// VALU-ISSUE-BOUND (VALUBusy 80%): r11 (-300 VALU staging ops) = -17%; r12/
// r13/r15/r18 (memory-side only) = flat; r17 (same VALU, worse mem) = slower.
// ||A-T||^2 = ||A||^2 + ||T||^2 - 2 A.T:
//  - ||A||^2: common-mode per anchor -> dropped (argmin-invariant).
//  - ||T||^2: precomputed ONCE in exact f64 (tiny kernels, partials+final
//    stashed in d_out, which gather fully overwrites afterwards).
//  - hot chain: 8-fma dot product (was 16 sub/fma) -> chain VALU x0.5.
// SAT keeps the identical fp32-8px-chain + f64-accumulate structure; argmin
// error ~2x today's ~7e-6 (12 consecutive absmax=0 runs -> ample margin).
// Staging/swizzle/occupancy identical to the 236us champion (r12/r18).

// 8-px fp32 DOT chain + f64 accumulate
#define CHAINAT(AV0, AV1, T0, T1, ACC) do { \
    float _s = (AV0).x * (T0).x; \
    _s = fmaf((AV0).y, (T0).y, _s); \
    _s = fmaf((AV0).z, (T0).z, _s); \
    _s = fmaf((AV0).w, (T0).w, _s); \
    _s = fmaf((AV1).x, (T1).x, _s); \
    _s = fmaf((AV1).y, (T1).y, _s); \
    _s = fmaf((AV1).z, (T1).z, _s); \
    _s = fmaf((AV1).w, (T1).w, _s); \
    (ACC) += (double)_s; } while(0)

__device__ __forceinline__ void async_copy16(const float* gp, float* lp) {
#if __has_builtin(__builtin_amdgcn_global_load_lds)
    __builtin_amdgcn_global_load_lds(
        (const __attribute__((address_space(1))) void*)gp,
        (__attribute__((address_space(3))) void*)lp, 16, 0, 0);
#else
    *(float4*)lp = *(const float4*)gp;
#endif
}

// ---- Sum t^2 per (y-row, target block), exact f64, partials to d_out ----
__global__ void __launch_bounds__(256) hbma_st2p_kernel(const float* __restrict__ T,
                                                        double* __restrict__ part) {
    const int t = blockIdx.x * 256 + threadIdx.x;
    if (t >= 8 * NBLK) return;
    const int y  = t / NBLK;
    const int b  = t - y * NBLK;
    const int gi = b / GW, gj = b % GW;
    const float* base = T + (size_t)(gi * 8 + y) * WW + gj * 8;
    double acc = 0.0;
    for (int q = 0; q < NP; ++q) {
        const float* r = base + (size_t)q * HWPX;
        const float4 v0 = *(const float4*)(r);
        const float4 v1 = *(const float4*)(r + 4);
        acc += (double)v0.x * v0.x + (double)v0.y * v0.y
             + (double)v0.z * v0.z + (double)v0.w * v0.w
             + (double)v1.x * v1.x + (double)v1.y * v1.y
             + (double)v1.z * v1.z + (double)v1.w * v1.w;
    }
    part[t] = acc;
}

__global__ void __launch_bounds__(256) hbma_st2c_kernel(const double* __restrict__ part,
                                                        double* __restrict__ stsum) {
    const int b = blockIdx.x * 256 + threadIdx.x;
    if (b >= NBLK) return;
    double s = 0.0;
#pragma unroll
    for (int y = 0; y < 8; ++y) s += part[y * NBLK + b];
    stsum[b] = s;
}

__global__ void __launch_bounds__(NTHR, 2)
hbma_cost_kernel(const float* __restrict__ A, const float* __restrict__ T,
                 const double* __restrict__ stsumF, int* __restrict__ bestidx) {
    extern __shared__ float lds[];
    float* Tt = lds;

    // XCD swizzle: 1360 WGs = 8 XCDs x 170
    const int lin = blockIdx.x;
    const int g   = (lin & 7) * (NWG / 8) + (lin >> 3);
    const int ig  = g % NIG, jg = g / NIG;
    const int i0  = ig * IT;
    const int j0  = jg * JT;

    const int tid = threadIdx.x;
    const int dy  = tid / 24;          // 0..8
    const int rem = tid % 24;
    const int it  = rem / 12;          // 0..1
    const int r2  = rem % 12;
    const int bg  = r2 >> 1;           // 0..5 (anchor pair)
    const int yh  = r2 & 1;            // y-half
    const bool act = (tid < NACT);
    const int i   = i0 + it;
    const int gi  = i + dy - 4;
    const bool dyValid = act && (i < GH) && (gi >= 0) && (gi < GH);
    const int dr  = it + dy;           // staged row index 0..9

    int xq[5];                         // per p-pair h: 4*((bg+h)&7) ^ 16*yh
#pragma unroll
    for (int h = 0; h < 5; ++h) xq[h] = (((bg + h) & 7) * 4) ^ (yh << 4);

    double acc0[9], acc1[9];           // SAT accumulators
#pragma unroll
    for (int d = 0; d < 9; ++d) { acc0[d] = 0.0; acc1[d] = 0.0; }

    const int gy0 = (i0 - 4) * 8;
    const int gx0 = (j0 - 4) * 8;
    const size_t arow0 = (size_t)(i * 8 + yh * 4) * WW;
    const int ja = (j0 + 2 * bg) * 8;

    for (int q = 0; q < NP; ++q) {
        const float* Tq = T + (size_t)q * HWPX;
        const float* Aq = A + (size_t)q * HWPX;
        __syncthreads();               // prev compute done before LDS overwrite
        // ---- stage target halo: async DMA, linear dest units, clamped src ----
        for (int w = tid; w < UNITS_TOT; w += NTHR) {
            const int dyr = w / UNITS_ROW;
            const int u   = w - dyr * UNITS_ROW;
            const int blk = u >> 4, v = u & 15;
            const int kb  = (blk >> 1) & 7;
            const int yh2 = v >> 3;
            const int m3  = (v & 7) ^ kb ^ (yh2 << 2);
            const int y   = (yh2 << 2) + (m3 >> 1);
            const int xh4 = m3 & 1;
            int gy = gy0 + dyr * 8 + y;
            int gx = gx0 + blk * 8 + xh4 * 4;
            gy = min(max(gy, 0), HH - 1);
            gx = min(max(gx, 0), WW - 4);
            async_copy16(Tq + (size_t)gy * WW + gx, Tt + dyr * DSTR + u * 4);
        }
        // ---- anchor rows -> registers (issue overlaps in-flight DMA) ----
        float4 ar[2][4][2];
        if (act && i < GH) {
#pragma unroll
            for (int a2 = 0; a2 < 2; ++a2) {
                const float* ap = Aq + (size_t)(j0 + 2 * bg + a2) * 8;
#pragma unroll
                for (int yi = 0; yi < 4; ++yi) {
                    const float* row = ap + (size_t)(i * 8 + yh * 4 + yi) * WW;
                    ar[a2][yi][0] = *(const float4*)(row);
                    ar[a2][yi][1] = *(const float4*)(row + 4);
                }
            }
        }
        __syncthreads();               // auto vmcnt(0): DMA landed
        // ---- SAT: sliding 10-block window serves 2 anchors x 9 dx ----
        if (dyValid) {
            const float* tb = Tt + dr * DSTR + bg * 128 + yh * 32;
#pragma unroll
            for (int yi = 0; yi < 4; ++yi) {
#pragma unroll
                for (int ph = 0; ph < 2; ++ph) {       // p-chunks of 5: 10-deep ds ILP
                    float4 tw0[5], tw1[5];
#pragma unroll
                    for (int pp = 0; pp < 5; ++pp) {
                        const int p  = ph * 5 + pp;
                        const int o0 = (yi * 8) ^ xq[p >> 1];
                        tw0[pp] = *(const float4*)(tb + p * 64 + o0);
                        tw1[pp] = *(const float4*)(tb + p * 64 + (o0 ^ 4));
                    }
#pragma unroll
                    for (int pp = 0; pp < 5; ++pp) {
                        const int p = ph * 5 + pp;
                        if (p < 9) CHAINAT(ar[0][yi][0], ar[0][yi][1], tw0[pp], tw1[pp], acc0[p]);
                        if (p > 0) CHAINAT(ar[1][yi][0], ar[1][yi][1], tw0[pp], tw1[pp], acc1[p - 1]);
                    }
                }
            }
        }
    }
    // ---- y-half merge via LDS (aliases Tt, barrier-protected) ----
    __syncthreads();
    double* yred = (double*)lds;                     // 108 pairs * 18 f64 = 3888 dw
    const int pairId = (it * NBG + bg) * 9 + dy;
    if (act && yh == 1) {
        double* d = yred + pairId * 18;
#pragma unroll
        for (int k = 0; k < 9; ++k) { d[k] = acc0[k]; d[9 + k] = acc1[k]; }
    }
    __syncthreads();
    double* redc = (double*)(lds + 8192);            // 216 f64 = 432 dw
    int*    redk = (int*)(lds + 8192 + 432);         // 216 int
    if (act && yh == 0) {
        const double* d = yred + pairId * 18;
#pragma unroll
        for (int k = 0; k < 9; ++k) { acc0[k] += d[k]; acc1[k] += d[9 + k]; }
        // stage-1 argmin over dx: V = stsum(exact f64) - 2*SAT  (SA dropped:
        // common-mode per anchor). Ascending dx, strict < -> first-k ties.
#pragma unroll
        for (int a2 = 0; a2 < 2; ++a2) {
            double bc = 1e300; int bk = -1;
            const int jb = j0 + 2 * bg + a2;
#pragma unroll
            for (int dxi = 0; dxi < 9; ++dxi) {
                const int gj = jb + dxi - 4;
                if (dyValid && gj >= 0 && gj < GW) {
                    const double sat = a2 ? acc1[dxi] : acc0[dxi];
                    const double c = stsumF[gi * GW + gj] - 2.0 * sat;
                    if (c < bc) { bc = c; bk = dy * 9 + dxi; }
                }
            }
            redc[(it * 9 + dy) * JT + 2 * bg + a2] = bc;
            redk[(it * 9 + dy) * JT + 2 * bg + a2] = bk;
        }
    }
    __syncthreads();
    // ---- stage-2 argmin over dy (ascending, strict <) ----
    if (tid < IT * JT) {
        const int it2 = tid / JT, jt = tid % JT;
        if (i0 + it2 < GH) {
            double c = 1e300; int k = -1;
#pragma unroll
            for (int dyi = 0; dyi < 9; ++dyi) {
                const double v = redc[(it2 * 9 + dyi) * JT + jt];
                if (v < c) { c = v; k = redk[(it2 * 9 + dyi) * JT + jt]; }
            }
            const int dyi = k / 9, dxi = k % 9;
            const int bi = i0 + it2 + dyi - 4;
            const int bj = j0 + jt + dxi - 4;
            bestidx[(i0 + it2) * GW + j0 + jt] = (bi << 8) | bj;
        }
    }
}

__global__ void __launch_bounds__(256) hbma_gather_kernel(const float* __restrict__ A,
                                                          const int* __restrict__ bestidx,
                                                          float* __restrict__ out) {
    const int tid = blockIdx.x * 256 + threadIdx.x;
    const int q   = tid / (HWPX / 4);
    const int rem = tid % (HWPX / 4);
    const int py  = rem / (WW / 4);
    const int c4  = rem % (WW / 4);
    const int i = py >> 3, y = py & 7;
    const int j = c4 >> 1, xh = (c4 & 1) * 4;
    const int idx = bestidx[i * GW + j];
    const int bi = idx >> 8, bj = idx & 255;
    const float4 v = *(const float4*)(A + (size_t)q * HWPX + (size_t)(bi * 8 + y) * WW + bj * 8 + xh);
    *(float4*)(out + (size_t)q * HWPX + (size_t)py * WW + c4 * 4) = v;
}

extern "C" void kernel_launch(void* const* d_in, const int* in_sizes, int n_in,
                              void* d_out, int out_size, void* d_ws, size_t ws_size,
                              hipStream_t stream) {
    const float* A = (const float*)d_in[0];
    const float* T = (const float*)d_in[1];
    float* out = (float*)d_out;
    int* bestidx = (int*)d_ws;

    // ||T||^2 scratch lives in d_out (fully overwritten by gather afterwards):
    // partials at double-index [0, 8*NBLK), final at ST2_FINAL_OFF.
    double* st2p = (double*)d_out;
    double* st2f = (double*)d_out + ST2_FINAL_OFF;

    hipFuncSetAttribute((const void*)hbma_cost_kernel,
                        hipFuncAttributeMaxDynamicSharedMemorySize, TT_DW * 4);

    hipLaunchKernelGGL(hbma_st2p_kernel, dim3((8 * NBLK + 255) / 256), dim3(256),
                       0, stream, T, st2p);
    hipLaunchKernelGGL(hbma_st2c_kernel, dim3((NBLK + 255) / 256), dim3(256),
                       0, stream, st2p, st2f);
    hipLaunchKernelGGL(hbma_cost_kernel, dim3(NWG), dim3(NTHR), TT_DW * 4, stream,
                       A, T, st2f, bestidx);

    const int total4 = (NP * HWPX) / 4;
    hipLaunchKernelGGL(hbma_gather_kernel, dim3(total4 / 256), dim3(256), 0, stream,
                       A, bestidx, out);
}

// Round 20
// 238.194 us; speedup vs baseline: 1.1201x; 1.1201x over previous
//
#include <hip/hip_runtime.h>

#define GH 135
#define GW 240
#define HH 1080
#define WW 1920
#define HWPX (HH*WW)
#define NP 12
#define IT 2               // anchor block-rows per WG (i-strip)
#define JT 12              // anchor blocks (j) per WG
#define NBG 6              // anchor pairs per it-row
#define NIG 68             // ceil(GH/IT)
#define NJG 20             // GW/JT
#define TROWS (IT+8)       // 10 staged target block-rows
#define TBLK (JT+8)        // 20 staged target blocks per dy-row
#define DSTR (TBLK*64+8)   // 1288 dw: 2-quad row rotation (r12 conflict fix)
#define UNITS_ROW (TBLK*16)// 320 16B-units per dy-row (= exactly 5 waves)
#define UNITS_TOT (TROWS*UNITS_ROW) // 3200
#define NTHR 256
#define NACT 216           // 9 dy * (2 it * 6 bg * 2 yh)
#define TT_DW (TROWS*DSTR) // 12880 dw = 51520 B -> 3 WG/CU at VGPR<=85
#define NWG (NIG*NJG)      // 1360 = 8*170 (XCD-exact)
#define NBLK (GH*GW)       // 32400 target blocks
#define ST2_FINAL_OFF 262144   // double-index into d_out for stsum

// Round-20 = r19's dot-product algebra with its two regressions repaired:
//  (1) VGPR 88 -> <=85: (256,3) + per-yi anchor loads (r18 style, 4 live
//      anchor regs not 16; r18 measured 76 with the HEAVIER chain) ->
//      restores 3 waves/SIMD (occupancy law: floor(256/VGPR)).
//  (2) st2 35us -> ~20us: single fused kernel, 1 thread/block, coalesced,
//      exact f64 squares, stsum direct to d_out scratch (gather overwrites).
// Algebra (r19, passed absmax 0): ||A-T||^2 = ||A||^2(drop) + ||T||^2(exact
// f64 precompute) - 2 A.T; hot chain = 8 fma (half of SSD's 16).
// Staging: async global_load_lds, linear dest units (5 whole waves/row),
// inverse-swizzled + clamped src (r11). Swizzle (bijective, r5/r12):
//   stored(blk,y,xh) = blk*64 + ((y*8+xh) ^ 4*kb ^ 16*(y>>2)), kb=(blk>>1)&7

// 8-px fp32 DOT chain + f64 accumulate (argmin-exact, proven r19)
#define CHAINAT(AV0, AV1, T0, T1, ACC) do { \
    float _s = (AV0).x * (T0).x; \
    _s = fmaf((AV0).y, (T0).y, _s); \
    _s = fmaf((AV0).z, (T0).z, _s); \
    _s = fmaf((AV0).w, (T0).w, _s); \
    _s = fmaf((AV1).x, (T1).x, _s); \
    _s = fmaf((AV1).y, (T1).y, _s); \
    _s = fmaf((AV1).z, (T1).z, _s); \
    _s = fmaf((AV1).w, (T1).w, _s); \
    (ACC) += (double)_s; } while(0)

__device__ __forceinline__ void async_copy16(const float* gp, float* lp) {
#if __has_builtin(__builtin_amdgcn_global_load_lds)
    __builtin_amdgcn_global_load_lds(
        (const __attribute__((address_space(1))) void*)gp,
        (__attribute__((address_space(3))) void*)lp, 16, 0, 0);
#else
    *(float4*)lp = *(const float4*)gp;
#endif
}

// ---- fused ||T||^2 per target block: exact f64, coalesced, one kernel ----
__global__ void __launch_bounds__(256) hbma_st2_kernel(const float* __restrict__ T,
                                                       double* __restrict__ stsum) {
    const int b = blockIdx.x * 256 + threadIdx.x;
    if (b >= NBLK) return;
    const int gi = b / GW, gj = b % GW;
    const float* base = T + (size_t)(gi * 8) * WW + gj * 8;
    double acc = 0.0;
    for (int q = 0; q < NP; ++q) {
        const float* pq = base + (size_t)q * HWPX;
#pragma unroll
        for (int y = 0; y < 8; ++y) {
            const float* r = pq + (size_t)y * WW;
            const float4 v0 = *(const float4*)(r);
            const float4 v1 = *(const float4*)(r + 4);
            acc += (double)v0.x * v0.x + (double)v0.y * v0.y
                 + (double)v0.z * v0.z + (double)v0.w * v0.w
                 + (double)v1.x * v1.x + (double)v1.y * v1.y
                 + (double)v1.z * v1.z + (double)v1.w * v1.w;
        }
    }
    stsum[b] = acc;
}

__global__ void __launch_bounds__(NTHR, 3)
hbma_cost_kernel(const float* __restrict__ A, const float* __restrict__ T,
                 const double* __restrict__ stsumF, int* __restrict__ bestidx) {
    extern __shared__ float lds[];
    float* Tt = lds;

    // XCD swizzle: 1360 WGs = 8 XCDs x 170
    const int lin = blockIdx.x;
    const int g   = (lin & 7) * (NWG / 8) + (lin >> 3);
    const int ig  = g % NIG, jg = g / NIG;
    const int i0  = ig * IT;
    const int j0  = jg * JT;

    const int tid = threadIdx.x;
    const int dy  = tid / 24;          // 0..8
    const int rem = tid % 24;
    const int it  = rem / 12;          // 0..1
    const int r2  = rem % 12;
    const int bg  = r2 >> 1;           // 0..5 (anchor pair)
    const int yh  = r2 & 1;            // y-half
    const bool act = (tid < NACT);
    const int i   = i0 + it;
    const int gi  = i + dy - 4;
    const bool dyValid = act && (i < GH) && (gi >= 0) && (gi < GH);
    const int dr  = it + dy;           // staged row index 0..9

    int xq[5];                         // per p-pair h: 4*((bg+h)&7) ^ 16*yh
#pragma unroll
    for (int h = 0; h < 5; ++h) xq[h] = (((bg + h) & 7) * 4) ^ (yh << 4);

    double acc0[9], acc1[9];           // SAT accumulators
#pragma unroll
    for (int d = 0; d < 9; ++d) { acc0[d] = 0.0; acc1[d] = 0.0; }

    const int gy0 = (i0 - 4) * 8;
    const int gx0 = (j0 - 4) * 8;
    const size_t arow0 = (size_t)(i * 8 + yh * 4) * WW;
    const int ja = (j0 + 2 * bg) * 8;

    for (int q = 0; q < NP; ++q) {
        const float* Tq = T + (size_t)q * HWPX;
        const float* Aq = A + (size_t)q * HWPX;
        __syncthreads();               // prev compute done before LDS overwrite
        // ---- stage target halo: async DMA, linear dest units, clamped src ----
        for (int w = tid; w < UNITS_TOT; w += NTHR) {
            const int dyr = w / UNITS_ROW;
            const int u   = w - dyr * UNITS_ROW;
            const int blk = u >> 4, v = u & 15;
            const int kb  = (blk >> 1) & 7;
            const int yh2 = v >> 3;
            const int m3  = (v & 7) ^ kb ^ (yh2 << 2);
            const int y   = (yh2 << 2) + (m3 >> 1);
            const int xh4 = m3 & 1;
            int gy = gy0 + dyr * 8 + y;
            int gx = gx0 + blk * 8 + xh4 * 4;
            gy = min(max(gy, 0), HH - 1);
            gx = min(max(gx, 0), WW - 4);
            async_copy16(Tq + (size_t)gy * WW + gx, Tt + dyr * DSTR + u * 4);
        }
        __syncthreads();               // auto vmcnt(0): DMA landed
        // ---- SAT: sliding 10-block window serves 2 anchors x 9 dx.
        //      Anchors loaded per-yi (4 live regs, L1-hot) to stay <=85 VGPR ----
        if (dyValid) {
            const float* tb = Tt + dr * DSTR + bg * 128 + yh * 32;
#pragma unroll
            for (int yi = 0; yi < 4; ++yi) {
                const float* arow_ = Aq + arow0 + (size_t)yi * WW + ja;
                const float4 aw0 = *(const float4*)(arow_);
                const float4 aw1 = *(const float4*)(arow_ + 4);
                const float4 aw2 = *(const float4*)(arow_ + 8);
                const float4 aw3 = *(const float4*)(arow_ + 12);
#pragma unroll
                for (int ph = 0; ph < 2; ++ph) {       // p-chunks of 5: 10-deep ds ILP
                    float4 tw0[5], tw1[5];
#pragma unroll
                    for (int pp = 0; pp < 5; ++pp) {
                        const int p  = ph * 5 + pp;
                        const int o0 = (yi * 8) ^ xq[p >> 1];
                        tw0[pp] = *(const float4*)(tb + p * 64 + o0);
                        tw1[pp] = *(const float4*)(tb + p * 64 + (o0 ^ 4));
                    }
#pragma unroll
                    for (int pp = 0; pp < 5; ++pp) {
                        const int p = ph * 5 + pp;
                        if (p < 9) CHAINAT(aw0, aw1, tw0[pp], tw1[pp], acc0[p]);
                        if (p > 0) CHAINAT(aw2, aw3, tw0[pp], tw1[pp], acc1[p - 1]);
                    }
                }
            }
        }
    }
    // ---- y-half merge via LDS (aliases Tt, barrier-protected) ----
    __syncthreads();
    double* yred = (double*)lds;                     // 108 pairs * 18 f64 = 3888 dw
    const int pairId = (it * NBG + bg) * 9 + dy;
    if (act && yh == 1) {
        double* d = yred + pairId * 18;
#pragma unroll
        for (int k = 0; k < 9; ++k) { d[k] = acc0[k]; d[9 + k] = acc1[k]; }
    }
    __syncthreads();
    double* redc = (double*)(lds + 8192);            // 216 f64 = 432 dw
    int*    redk = (int*)(lds + 8192 + 432);         // 216 int
    if (act && yh == 0) {
        const double* d = yred + pairId * 18;
#pragma unroll
        for (int k = 0; k < 9; ++k) { acc0[k] += d[k]; acc1[k] += d[9 + k]; }
        // stage-1 argmin over dx: V = stsum(exact f64) - 2*SAT.
        // Ascending dx, strict < -> first-k ties (matches np argmin).
#pragma unroll
        for (int a2 = 0; a2 < 2; ++a2) {
            double bc = 1e300; int bk = -1;
            const int jb = j0 + 2 * bg + a2;
#pragma unroll
            for (int dxi = 0; dxi < 9; ++dxi) {
                const int gj = jb + dxi - 4;
                if (dyValid && gj >= 0 && gj < GW) {
                    const double sat = a2 ? acc1[dxi] : acc0[dxi];
                    const double c = stsumF[gi * GW + gj] - 2.0 * sat;
                    if (c < bc) { bc = c; bk = dy * 9 + dxi; }
                }
            }
            redc[(it * 9 + dy) * JT + 2 * bg + a2] = bc;
            redk[(it * 9 + dy) * JT + 2 * bg + a2] = bk;
        }
    }
    __syncthreads();
    // ---- stage-2 argmin over dy (ascending, strict <) ----
    if (tid < IT * JT) {
        const int it2 = tid / JT, jt = tid % JT;
        if (i0 + it2 < GH) {
            double c = 1e300; int k = -1;
#pragma unroll
            for (int dyi = 0; dyi < 9; ++dyi) {
                const double v = redc[(it2 * 9 + dyi) * JT + jt];
                if (v < c) { c = v; k = redk[(it2 * 9 + dyi) * JT + jt]; }
            }
            const int dyi = k / 9, dxi = k % 9;
            const int bi = i0 + it2 + dyi - 4;
            const int bj = j0 + jt + dxi - 4;
            bestidx[(i0 + it2) * GW + j0 + jt] = (bi << 8) | bj;
        }
    }
}

__global__ void __launch_bounds__(256) hbma_gather_kernel(const float* __restrict__ A,
                                                          const int* __restrict__ bestidx,
                                                          float* __restrict__ out) {
    const int tid = blockIdx.x * 256 + threadIdx.x;
    const int q   = tid / (HWPX / 4);
    const int rem = tid % (HWPX / 4);
    const int py  = rem / (WW / 4);
    const int c4  = rem % (WW / 4);
    const int i = py >> 3, y = py & 7;
    const int j = c4 >> 1, xh = (c4 & 1) * 4;
    const int idx = bestidx[i * GW + j];
    const int bi = idx >> 8, bj = idx & 255;
    const float4 v = *(const float4*)(A + (size_t)q * HWPX + (size_t)(bi * 8 + y) * WW + bj * 8 + xh);
    *(float4*)(out + (size_t)q * HWPX + (size_t)py * WW + c4 * 4) = v;
}

extern "C" void kernel_launch(void* const* d_in, const int* in_sizes, int n_in,
                              void* d_out, int out_size, void* d_ws, size_t ws_size,
                              hipStream_t stream) {
    const float* A = (const float*)d_in[0];
    const float* T = (const float*)d_in[1];
    float* out = (float*)d_out;
    int* bestidx = (int*)d_ws;

    // ||T||^2 scratch in d_out (gather fully overwrites it afterwards)
    double* st2f = (double*)d_out + ST2_FINAL_OFF;

    hipFuncSetAttribute((const void*)hbma_cost_kernel,
                        hipFuncAttributeMaxDynamicSharedMemorySize, TT_DW * 4);

    hipLaunchKernelGGL(hbma_st2_kernel, dim3((NBLK + 255) / 256), dim3(256),
                       0, stream, T, st2f);
    hipLaunchKernelGGL(hbma_cost_kernel, dim3(NWG), dim3(NTHR), TT_DW * 4, stream,
                       A, T, st2f, bestidx);

    const int total4 = (NP * HWPX) / 4;
    hipLaunchKernelGGL(hbma_gather_kernel, dim3(total4 / 256), dim3(256), 0, stream,
                       A, bestidx, out);
}

// Round 21
// 228.310 us; speedup vs baseline: 1.1686x; 1.0433x over previous
//
#include <hip/hip_runtime.h>

#define GH 135
#define GW 240
#define HH 1080
#define WW 1920
#define HWPX (HH*WW)
#define NP 12
#define IT 6               // anchor block-rows per WG
#define JT 6               // anchor blocks (j) per WG
#define NTG 2              // anchor TRIPLES per it-row (3 anchors/thread)
#define NIG 23             // ceil(GH/IT), last strip ragged (guarded)
#define NJG 40             // GW/JT
#define TROWS (IT+8)       // 14 staged target block-rows
#define TBLK (JT+8)        // 14 REAL staged blocks per dy-row
#define TSBLK 16           // STORED blocks/row: UNITS_ROW=256 = 4 whole waves
                           // (global_load_lds wave-uniform-base rule, r15)
#define DSTR (TSBLK*64+8)  // 1032 dw: 2-quad row rotation (r12)
#define UNITS_ROW (TSBLK*16) // 256 units = 4 waves exactly
#define NTHR 256
#define NACT 216           // 9 dy * (6 it * 2 tg * 2 yh) = 84% active
#define TT_DW (TROWS*DSTR) // 14448 dw = 57792 B -> 2 WG/CU at VGPR<=128
#define NWG (NIG*NJG)      // 920 = 8*115 (XCD-exact)
#define NBLK (GH*GW)       // 32400 target blocks
#define ST2_FINAL_OFF 262144   // double-index into d_out for stsum

// Round-21, two independent per-kernel levers:
//  (1) st2: 32us -> ~18us. Was 127 WGs (half GPU idle) x 1152-long serial f64
//      chain. Now (block, y, q-half) slices: 2025 WGs, 48 MACs/thread, lanes
//      laid out b16=tid&15 for contiguous 512B/16-lane reads, LDS merge.
//  (2) cost: A=3 windows (LDS reads/anchor x0.73 — LDS is now the ~63% pole
//      after r20 halved chain VALU). Structure = r15 verbatim (proven absmax
//      0), chain = CHAINAT dot (r19/r20), argmin = stsum - 2*SAT (r20).
// Occupancy law (r5-r10): (256,2) -> cap 128; r15 measured exactly 128.
// Swizzle (bijective, r5/r12): stored(blk,y,xh)=blk*64+((y*8+xh)^4*kb^16*(y>>2))

// 8-px fp32 DOT chain + f64 accumulate (argmin-exact, proven r19/r20)
#define CHAINAT(AV0, AV1, T0, T1, ACC) do { \
    float _s = (AV0).x * (T0).x; \
    _s = fmaf((AV0).y, (T0).y, _s); \
    _s = fmaf((AV0).z, (T0).z, _s); \
    _s = fmaf((AV0).w, (T0).w, _s); \
    _s = fmaf((AV1).x, (T1).x, _s); \
    _s = fmaf((AV1).y, (T1).y, _s); \
    _s = fmaf((AV1).z, (T1).z, _s); \
    _s = fmaf((AV1).w, (T1).w, _s); \
    (ACC) += (double)_s; } while(0)

__device__ __forceinline__ void async_copy16(const float* gp, float* lp) {
#if __has_builtin(__builtin_amdgcn_global_load_lds)
    __builtin_amdgcn_global_load_lds(
        (const __attribute__((address_space(1))) void*)gp,
        (__attribute__((address_space(3))) void*)lp, 16, 0, 0);
#else
    *(float4*)lp = *(const float4*)gp;
#endif
}

// ---- ||T||^2 per target block: 16 blocks x 16 (y,qh) slices per WG ----
__global__ void __launch_bounds__(256) hbma_st2_kernel(const float* __restrict__ T,
                                                       double* __restrict__ stsum) {
    __shared__ double red[256];
    const int tid = threadIdx.x;
    const int b16 = tid & 15;          // block within WG (fast -> coalesced)
    const int s   = tid >> 4;          // slice: y = s&7, qh = s>>3
    const int bb  = blockIdx.x * 16 + b16;
    const int gi = bb / GW, gj = bb % GW;
    const int y  = s & 7, qh = s >> 3;
    const float* base = T + (size_t)(gi * 8 + y) * WW + gj * 8 + (size_t)(qh * 6) * HWPX;
    double acc = 0.0;
#pragma unroll
    for (int q = 0; q < 6; ++q) {
        const float* r = base + (size_t)q * HWPX;
        const float4 v0 = *(const float4*)(r);
        const float4 v1 = *(const float4*)(r + 4);
        acc += (double)v0.x * v0.x + (double)v0.y * v0.y
             + (double)v0.z * v0.z + (double)v0.w * v0.w
             + (double)v1.x * v1.x + (double)v1.y * v1.y
             + (double)v1.z * v1.z + (double)v1.w * v1.w;
    }
    red[s * 16 + b16] = acc;
    __syncthreads();
    if (tid < 16) {                    // one summer per target block
        double t = 0.0;
#pragma unroll
        for (int k = 0; k < 16; ++k) t += red[k * 16 + tid];
        stsum[blockIdx.x * 16 + tid] = t;
    }
}

__global__ void __launch_bounds__(NTHR, 2)
hbma_cost_kernel(const float* __restrict__ A, const float* __restrict__ T,
                 const double* __restrict__ stsumF, int* __restrict__ bestidx) {
    extern __shared__ float lds[];
    float* Tt = lds;

    // XCD swizzle: 920 WGs = 8 XCDs x 115
    const int lin = blockIdx.x;
    const int g   = (lin & 7) * (NWG / 8) + (lin >> 3);
    const int ig  = g % NIG, jg = g / NIG;
    const int i0  = ig * IT;
    const int j0  = jg * JT;

    const int tid = threadIdx.x;
    const int dy  = tid / 24;          // 0..8 for active threads
    const int rem = tid % 24;
    const int it  = rem >> 2;          // 0..5
    const int r2  = rem & 3;
    const int tg  = r2 >> 1;           // 0..1 (anchor triple)
    const int yh  = r2 & 1;            // y-half
    const bool act = (tid < NACT);
    const int i   = i0 + it;           // may be >= GH on last strip (guarded)
    const int gi  = i + dy - 4;
    const bool dyValid = act && (i < GH) && (gi >= 0) && (gi < GH);
    const int dr  = it + dy;           // staged row index 0..13
    const int jb0 = j0 + 3 * tg;       // first anchor block of this thread

    // per-p read XOR (window base 3*tg may be odd); static-indexed -> registers
    int xq2[11];
#pragma unroll
    for (int p = 0; p < 11; ++p)
        xq2[p] = ((((3 * tg + p) >> 1) & 7) * 4) ^ (yh << 4);

    double acc[3][9];                  // SAT accumulators
#pragma unroll
    for (int a = 0; a < 3; ++a)
#pragma unroll
        for (int d = 0; d < 9; ++d) acc[a][d] = 0.0;

    const int gy0 = (i0 - 4) * 8;
    const int gx0 = (j0 - 4) * 8;

    for (int q = 0; q < NP; ++q) {
        const float* Tq = T + (size_t)q * HWPX;
        const float* Aq = A + (size_t)q * HWPX;
        __syncthreads();               // prev compute done before LDS overwrite
        // ---- stage: 14 full rows, each = 256 units = 4 whole waves (r15) ----
#pragma unroll 1
        for (int k = 0; k < TROWS; ++k) {
            const int u   = tid;
            const int blk = u >> 4, v = u & 15;
            const int kb  = (blk >> 1) & 7;
            const int yh2 = v >> 3;
            const int m3  = (v & 7) ^ kb ^ (yh2 << 2);
            const int y   = (yh2 << 2) + (m3 >> 1);
            const int xh4 = m3 & 1;
            int gy = gy0 + k * 8 + y;
            int gx = gx0 + blk * 8 + xh4 * 4;   // blk 14/15 = pad, never read
            gy = min(max(gy, 0), HH - 1);       // clamp: garbage slots are
            gx = min(max(gx, 0), WW - 4);       // argmin-masked (r11)
            async_copy16(Tq + (size_t)gy * WW + gx, Tt + k * DSTR + u * 4);
        }
        __syncthreads();               // auto vmcnt(0): DMA landed
        // ---- SAT: sliding 11-block window serves 3 anchors x 9 dx ----
        if (dyValid) {
            const float* tb = Tt + dr * DSTR + (3 * tg) * 64 + yh * 32;
#pragma unroll
            for (int yi = 0; yi < 4; ++yi) {
                float4 aw[3][2];       // per-yi anchor rows (L1-hot, 9x redundant)
#pragma unroll
                for (int a = 0; a < 3; ++a) {
                    const float* row = Aq + (size_t)(jb0 + a) * 8
                                     + (size_t)(i * 8 + yh * 4 + yi) * WW;
                    aw[a][0] = *(const float4*)(row);
                    aw[a][1] = *(const float4*)(row + 4);
                }
#pragma unroll
                for (int ph = 0; ph < 3; ++ph) {   // p-chunks 4/4/3
                    const int pc = (ph < 2) ? 4 : 3;
                    float4 tw0[4], tw1[4];
#pragma unroll
                    for (int pp = 0; pp < 4; ++pp) {
                        if (pp < pc) {
                            const int p  = ph * 4 + pp;
                            const int o0 = (yi * 8) ^ xq2[p];
                            tw0[pp] = *(const float4*)(tb + p * 64 + o0);
                            tw1[pp] = *(const float4*)(tb + p * 64 + (o0 ^ 4));
                        }
                    }
#pragma unroll
                    for (int pp = 0; pp < 4; ++pp) {
                        if (pp < pc) {
                            const int p = ph * 4 + pp;
#pragma unroll
                            for (int a = 0; a < 3; ++a) {
                                const int dxi = p - a;
                                if (dxi >= 0 && dxi < 9)
                                    CHAINAT(aw[a][0], aw[a][1], tw0[pp], tw1[pp], acc[a][dxi]);
                            }
                        }
                    }
                }
            }
        }
    }
    // ---- y-half merge via LDS (aliases Tt, barrier-protected) ----
    __syncthreads();
    double* yred = (double*)lds;                     // 108 groups * 27 f64
    const int grpId = (it * NTG + tg) * 9 + dy;      // 0..107
    if (act && yh == 1) {
        double* d = yred + grpId * 27;
#pragma unroll
        for (int a = 0; a < 3; ++a)
#pragma unroll
            for (int k = 0; k < 9; ++k) d[a * 9 + k] = acc[a][k];
    }
    __syncthreads();
    double* redc = (double*)(lds + 8192);            // 324 f64
    int*    redk = (int*)(lds + 8192 + 648);         // 324 int
    if (act && yh == 0) {
        const double* d = yred + grpId * 27;
#pragma unroll
        for (int a = 0; a < 3; ++a)
#pragma unroll
            for (int k = 0; k < 9; ++k) acc[a][k] += d[a * 9 + k];
        // stage-1 argmin over dx: V = stsum(exact f64) - 2*SAT.
        // Ascending dx, strict < -> first-k ties (matches np argmin).
#pragma unroll
        for (int a = 0; a < 3; ++a) {
            double bc = 1e300; int bk = -1;
            const int jb = jb0 + a;
#pragma unroll
            for (int dxi = 0; dxi < 9; ++dxi) {
                const int gj = jb + dxi - 4;
                if (dyValid && gj >= 0 && gj < GW) {
                    const double c = stsumF[gi * GW + gj] - 2.0 * acc[a][dxi];
                    if (c < bc) { bc = c; bk = dy * 9 + dxi; }
                }
            }
            redc[(it * 9 + dy) * JT + 3 * tg + a] = bc;
            redk[(it * 9 + dy) * JT + 3 * tg + a] = bk;
        }
    }
    __syncthreads();
    // ---- stage-2 argmin over dy (ascending, strict <) ----
    if (tid < IT * JT) {
        const int it2 = tid / JT, jt = tid % JT;
        if (i0 + it2 < GH) {
            double c = 1e300; int k = -1;
#pragma unroll
            for (int dyi = 0; dyi < 9; ++dyi) {
                const double v = redc[(it2 * 9 + dyi) * JT + jt];
                if (v < c) { c = v; k = redk[(it2 * 9 + dyi) * JT + jt]; }
            }
            const int dyi = k / 9, dxi = k % 9;
            const int bi = i0 + it2 + dyi - 4;
            const int bj = j0 + jt + dxi - 4;
            bestidx[(i0 + it2) * GW + j0 + jt] = (bi << 8) | bj;
        }
    }
}

__global__ void __launch_bounds__(256) hbma_gather_kernel(const float* __restrict__ A,
                                                          const int* __restrict__ bestidx,
                                                          float* __restrict__ out) {
    const int tid = blockIdx.x * 256 + threadIdx.x;
    const int q   = tid / (HWPX / 4);
    const int rem = tid % (HWPX / 4);
    const int py  = rem / (WW / 4);
    const int c4  = rem % (WW / 4);
    const int i = py >> 3, y = py & 7;
    const int j = c4 >> 1, xh = (c4 & 1) * 4;
    const int idx = bestidx[i * GW + j];
    const int bi = idx >> 8, bj = idx & 255;
    const float4 v = *(const float4*)(A + (size_t)q * HWPX + (size_t)(bi * 8 + y) * WW + bj * 8 + xh);
    *(float4*)(out + (size_t)q * HWPX + (size_t)py * WW + c4 * 4) = v;
}

extern "C" void kernel_launch(void* const* d_in, const int* in_sizes, int n_in,
                              void* d_out, int out_size, void* d_ws, size_t ws_size,
                              hipStream_t stream) {
    const float* A = (const float*)d_in[0];
    const float* T = (const float*)d_in[1];
    float* out = (float*)d_out;
    int* bestidx = (int*)d_ws;

    // ||T||^2 scratch in d_out (gather fully overwrites it afterwards)
    double* st2f = (double*)d_out + ST2_FINAL_OFF;

    hipFuncSetAttribute((const void*)hbma_cost_kernel,
                        hipFuncAttributeMaxDynamicSharedMemorySize, TT_DW * 4);

    hipLaunchKernelGGL(hbma_st2_kernel, dim3(NBLK / 16), dim3(256),
                       0, stream, T, st2f);
    hipLaunchKernelGGL(hbma_cost_kernel, dim3(NWG), dim3(NTHR), TT_DW * 4, stream,
                       A, T, st2f, bestidx);

    const int total4 = (NP * HWPX) / 4;
    hipLaunchKernelGGL(hbma_gather_kernel, dim3(total4 / 256), dim3(256), 0, stream,
                       A, bestidx, out);
}